// Round 13
// baseline (11731.201 us; speedup 1.0000x reference)
//
#include <hip/hip_runtime.h>

#define BSZ   8192
#define NAG   16
#define NOBSZ 512
#define HSZ   64

typedef _Float16 h2    __attribute__((ext_vector_type(2)));
typedef _Float16 f16x8 __attribute__((ext_vector_type(8)));
typedef float    f32x4 __attribute__((ext_vector_type(4)));

__device__ __forceinline__ float sigmoid_f(float x) { return 1.f / (1.f + __expf(-x)); }
__device__ __forceinline__ float tanh_f(float x)    { float e = __expf(2.f * x); return 1.f - 2.f / (e + 1.f); }

// lgkm-only barrier: orders LDS traffic without draining vmcnt (X prefetch
// and hid stores stay in flight). The "memory" clobber also pins compiler
// ordering of LDS accesses around it.
__device__ __forceinline__ void lds_barrier() {
    asm volatile("s_waitcnt lgkmcnt(0)" ::: "memory");
    __builtin_amdgcn_s_barrier();
    asm volatile("" ::: "memory");
}

__device__ __forceinline__ int packh2(float x, float y) {
    h2 p; p.x = (_Float16)x; p.y = (_Float16)y;
    return __builtin_bit_cast(int, p);
}

// ---------------------------------------------------------------------------
// Encode: per-agent  e1 = relu(obs@W1^T+b1)  -> e2 = relu(e1@W2^T+b2)
//         X = (e2 + comm_t) @ W_ih^T + (b_ih + b_hh)
// One workgroup = (agent n, 64 batch rows). 256 threads, fp32, LDS-tiled.
// ---------------------------------------------------------------------------
__global__ __launch_bounds__(256, 2) void encode_kernel(
    const float* __restrict__ obs, const float* __restrict__ comm,
    const float* __restrict__ W1,  const float* __restrict__ b1,
    const float* __restrict__ W2,  const float* __restrict__ b2,
    const float* __restrict__ Wih, const float* __restrict__ bih,
    const float* __restrict__ bhh, float* __restrict__ X)
{
    __shared__ float lds[20480];            // 80 KB -> 2 blocks/CU
    const int n  = blockIdx.y;
    const int bt = blockIdx.x;              // rows bt*64 .. bt*64+63
    const int t  = threadIdx.x;
    const int ty = t >> 4, tx = t & 15;

    float* sA   = lds;                      // [32][64]   GEMM1 A-tile (k-major)
    float* sW   = lds + 2048;               // [32][128]  GEMM1 W-tile (k-major)
    float* sW2  = lds;                      // [128][64]  GEMM2 W (aliases sA/sW)
    float* sE1  = lds + 8192;               // [128][64]  e1 (k-major)
    float* sE2  = lds + 16384;              // [64][64]   e2 (k-major)
    float* sWih = lds;                      // [64][256]  W_ih (aliases [0,16384))

    // ---------------- GEMM1: K=512, out 64x128 ----------------
    float acc1[4][2][4];
    #pragma unroll
    for (int i = 0; i < 4; i++)
        #pragma unroll
        for (int c = 0; c < 2; c++)
            #pragma unroll
            for (int j = 0; j < 4; j++) acc1[i][c][j] = 0.f;

    const float* obsn = obs + ((size_t)bt * 64 * NAG + n) * NOBSZ;
    const int rA = t >> 2, sgA = t & 3;     // A staging: 4 threads/row
    const int hW = t >> 1, sbW = (t & 1) * 4; // W staging: 2 threads/row

    for (int k0 = 0; k0 < NOBSZ; k0 += 32) {
        {   // stage A-tile (64 x 32), coalesced float4 loads, k-major LDS
            const float* src = obsn + (size_t)rA * (NAG * NOBSZ) + k0 + sgA * 4;
            float4 v0 = *(const float4*)src;
            float4 v1 = *(const float4*)(src + 16);
            sA[(sgA*4+ 0)*64 + rA] = v0.x; sA[(sgA*4+ 1)*64 + rA] = v0.y;
            sA[(sgA*4+ 2)*64 + rA] = v0.z; sA[(sgA*4+ 3)*64 + rA] = v0.w;
            sA[(sgA*4+16)*64 + rA] = v1.x; sA[(sgA*4+17)*64 + rA] = v1.y;
            sA[(sgA*4+18)*64 + rA] = v1.z; sA[(sgA*4+19)*64 + rA] = v1.w;
        }
        {   // stage W1-tile (128 x 32)
            const float* src = W1 + ((size_t)n * 128 + hW) * NOBSZ + k0;
            #pragma unroll
            for (int u = 0; u < 4; u++) {
                float4 v = *(const float4*)(src + (sbW + u) * 4);
                sW[((sbW+u)*4+0)*128 + hW] = v.x;
                sW[((sbW+u)*4+1)*128 + hW] = v.y;
                sW[((sbW+u)*4+2)*128 + hW] = v.z;
                sW[((sbW+u)*4+3)*128 + hW] = v.w;
            }
        }
        __syncthreads();
        #pragma unroll 8
        for (int kk = 0; kk < 32; ++kk) {
            float4 a   = *(const float4*)&sA[kk*64 + ty*4];
            float4 bv0 = *(const float4*)&sW[kk*128 + tx*4];
            float4 bv1 = *(const float4*)&sW[kk*128 + 64 + tx*4];
            float av[4] = {a.x, a.y, a.z, a.w};
            float w0[4] = {bv0.x, bv0.y, bv0.z, bv0.w};
            float w1[4] = {bv1.x, bv1.y, bv1.z, bv1.w};
            #pragma unroll
            for (int i = 0; i < 4; i++) {
                #pragma unroll
                for (int j = 0; j < 4; j++) {
                    acc1[i][0][j] += av[i] * w0[j];
                    acc1[i][1][j] += av[i] * w1[j];
                }
            }
        }
        __syncthreads();
    }
    {   // epilogue 1: relu(+b1) -> sE1 (k-major)
        const float* b1n = b1 + n * 128;
        #pragma unroll
        for (int i = 0; i < 4; i++) {
            int row = ty * 4 + i;
            #pragma unroll
            for (int c = 0; c < 2; c++) {
                #pragma unroll
                for (int j = 0; j < 4; j++) {
                    int col = c * 64 + tx * 4 + j;
                    sE1[col * 64 + row] = fmaxf(acc1[i][c][j] + b1n[col], 0.f);
                }
            }
        }
    }
    {   // stage W2 (64 x 128) into region P (sA/sW dead after last barrier)
        const int h = t >> 2, ks = t & 3;
        const float* src = W2 + ((size_t)n * 64 + h) * 128;
        #pragma unroll
        for (int u = 0; u < 8; u++) {
            int s = ks + 4 * u;
            float4 v = *(const float4*)(src + s * 4);
            sW2[(s*4+0)*64 + h] = v.x;
            sW2[(s*4+1)*64 + h] = v.y;
            sW2[(s*4+2)*64 + h] = v.z;
            sW2[(s*4+3)*64 + h] = v.w;
        }
    }
    __syncthreads();

    // ---------------- GEMM2: K=128, out 64x64 ----------------
    float acc2[4][4];
    #pragma unroll
    for (int i = 0; i < 4; i++)
        #pragma unroll
        for (int j = 0; j < 4; j++) acc2[i][j] = 0.f;
    #pragma unroll 8
    for (int kk = 0; kk < 128; ++kk) {
        float4 a = *(const float4*)&sE1[kk*64 + ty*4];
        float4 w = *(const float4*)&sW2[kk*64 + tx*4];
        float av[4] = {a.x, a.y, a.z, a.w};
        float wv[4] = {w.x, w.y, w.z, w.w};
        #pragma unroll
        for (int i = 0; i < 4; i++)
            #pragma unroll
            for (int j = 0; j < 4; j++) acc2[i][j] += av[i] * wv[j];
    }
    __syncthreads();                        // sE1/sW2 reads done
    {   // epilogue 2: relu(+b2) + comm_t -> sE2 (k-major)
        const float* b2n = b2 + n * 64;
        #pragma unroll
        for (int i = 0; i < 4; i++) {
            int row = ty * 4 + i;
            #pragma unroll
            for (int j = 0; j < 4; j++) {
                int col = tx * 4 + j;
                float v = fmaxf(acc2[i][j] + b2n[col], 0.f) + comm[col * NAG + n];
                sE2[col * 64 + row] = v;
            }
        }
    }
    {   // stage W_ih (256 x 64) -> sWih[k][r]
        const float* src = Wih + t * 64;
        #pragma unroll
        for (int u = 0; u < 16; u++) {
            float4 v = *(const float4*)(src + u * 4);
            sWih[(u*4+0)*256 + t] = v.x;
            sWih[(u*4+1)*256 + t] = v.y;
            sWih[(u*4+2)*256 + t] = v.z;
            sWih[(u*4+3)*256 + t] = v.w;
        }
    }
    __syncthreads();

    // ---------------- GEMM3: K=64, out 64x256 (two halves to cap VGPRs) ----
    for (int half = 0; half < 2; ++half) {
        float acc3[4][2][4];
        #pragma unroll
        for (int i = 0; i < 4; i++)
            #pragma unroll
            for (int c = 0; c < 2; c++)
                #pragma unroll
                for (int j = 0; j < 4; j++) acc3[i][c][j] = 0.f;
        #pragma unroll 4
        for (int kk = 0; kk < 64; ++kk) {
            float4 a = *(const float4*)&sE2[kk*64 + ty*4];
            float av[4] = {a.x, a.y, a.z, a.w};
            #pragma unroll
            for (int c = 0; c < 2; c++) {
                int col0 = (half * 2 + c) * 64 + tx * 4;
                float4 w = *(const float4*)&sWih[kk*256 + col0];
                float wv[4] = {w.x, w.y, w.z, w.w};
                #pragma unroll
                for (int i = 0; i < 4; i++)
                    #pragma unroll
                    for (int j = 0; j < 4; j++) acc3[i][c][j] += av[i] * wv[j];
            }
        }
        #pragma unroll
        for (int i = 0; i < 4; i++) {
            int b = bt * 64 + ty * 4 + i;
            float* dst = X + ((size_t)b * NAG + n) * 256;
            #pragma unroll
            for (int c = 0; c < 2; c++) {
                int col0 = (half * 2 + c) * 64 + tx * 4;
                float4 bi = *(const float4*)(bih + col0);
                float4 bh = *(const float4*)(bhh + col0);
                float4 o;
                o.x = acc3[i][c][0] + bi.x + bh.x;
                o.y = acc3[i][c][1] + bi.y + bh.y;
                o.z = acc3[i][c][2] + bi.z + bh.z;
                o.w = acc3[i][c][3] + bi.w + bh.w;
                *(float4*)(dst + col0) = o;
            }
        }
    }
}

// ---------------------------------------------------------------------------
// Scan via MATRIX CORES: all 16 agents share W_hh, so each step is one
// matmul G(256x16) = W_hh(256x64) @ H(64x16). One block, 4 waves; wave w
// owns gate w (64 rows = 4 M-tiles x 2 K-tiles = 8 mfma_f32_16x16x32_f16
// per step). Weights live as 8 A-fragments read DIRECTLY by MFMA from the
// accumulator file -> zero operand-supply VALU instructions (R12 showed the
// v_dot2 design pays ~330 shuttle instr/step). X is the MFMA C-in (free
// accumulate). C/D layout (HW-verified): col=lane&15, row=(lane>>4)*4+reg.
// A: row=lane&15, k=(lane>>4)*8+e. B: col=lane&15, k=(lane>>4)*8+e.
// Two lgkm-only barriers/step: gate exchange, h exchange.
// ---------------------------------------------------------------------------
__global__ __launch_bounds__(256, 1) void scan_kernel(
    const float* __restrict__ X, const float* __restrict__ Whh,
    const float* __restrict__ lstm_h, const float* __restrict__ lstm_s,
    float* __restrict__ hid)
{
    __shared__ float g_lds[16][64][4];      // [gate*4+mtile][lane][reg] activated gates
    __shared__ int   hp_lds[16][36];        // h as packed f16 pairs, [agent][pair], pad->36
    const int t  = threadIdx.x;
    const int wv = t >> 6;                  // wave = gate (0:i 1:f 2:g 3:o)
    const int l  = t & 63;
    const int a  = l & 15;                  // agent col (C/B) == A-row-within-tile
    const int rg = l >> 4;                  // lane group

    // ---- A fragments: W_hh rows 64wv..64wv+63, f32 -> f16, k ascending ----
    f16x8 afrag[4][2];
    #pragma unroll
    for (int mt = 0; mt < 4; mt++)
        #pragma unroll
        for (int kt = 0; kt < 2; kt++) {
            const float* src = Whh + (size_t)(64*wv + mt*16 + a) * 64 + kt*32 + rg*8;
            float4 v0 = *(const float4*)src;
            float4 v1 = *(const float4*)(src + 4);
            f16x8 f;
            f[0]=(_Float16)v0.x; f[1]=(_Float16)v0.y; f[2]=(_Float16)v0.z; f[3]=(_Float16)v0.w;
            f[4]=(_Float16)v1.x; f[5]=(_Float16)v1.y; f[6]=(_Float16)v1.z; f[7]=(_Float16)v1.w;
            afrag[mt][kt] = f;
        }

    // ---- initial B fragments from lstm_h ((1,1,H,N): H[cell][agent]) ----
    f16x8 bfrag[2];
    #pragma unroll
    for (int kt = 0; kt < 2; kt++) {
        f16x8 f;
        #pragma unroll
        for (int e = 0; e < 8; e++) {
            int k = kt*32 + rg*8 + e;
            f[e] = (_Float16)lstm_h[k * NAG + a];
        }
        bfrag[kt] = f;
    }

    // ---- c state: thread owns cells wv*16+rg*4+r (r=0..3) of agent a ----
    float cst[4];
    #pragma unroll
    for (int r = 0; r < 4; r++) cst[r] = lstm_s[(wv*16 + rg*4 + r) * NAG + a];

    const float* Xb = X + a*256 + 64*wv + rg*4;     // + b*4096 + mt*16
    float*       hq = hid + a*64 + wv*16 + rg*4;    // + b*1024

    float4 xa[4], xb[4];
    #pragma unroll
    for (int mt = 0; mt < 4; mt++) xa[mt] = *(const float4*)(Xb + mt*16);

    auto step = [&](int b, float4 (&xc)[4]) {
        // ---- G = W.H + X : 8 MFMAs, C-in = X fragment ----
        f32x4 g[4];
        #pragma unroll
        for (int mt = 0; mt < 4; mt++) {
            g[mt] = __builtin_amdgcn_mfma_f32_16x16x32_f16(
                        afrag[mt][0], bfrag[0],
                        __builtin_bit_cast(f32x4, xc[mt]), 0, 0, 0);
            g[mt] = __builtin_amdgcn_mfma_f32_16x16x32_f16(
                        afrag[mt][1], bfrag[1], g[mt], 0, 0, 0);
        }
        // ---- gate nonlinearity (uniform branch per wave) ----
        if (wv == 2) {
            #pragma unroll
            for (int mt = 0; mt < 4; mt++)
                #pragma unroll
                for (int r = 0; r < 4; r++) g[mt][r] = tanh_f(g[mt][r]);
        } else {
            #pragma unroll
            for (int mt = 0; mt < 4; mt++)
                #pragma unroll
                for (int r = 0; r < 4; r++) g[mt][r] = sigmoid_f(g[mt][r]);
        }
        #pragma unroll
        for (int mt = 0; mt < 4; mt++)
            *(float4*)&g_lds[wv*4 + mt][l][0] = __builtin_bit_cast(float4, g[mt]);
        lds_barrier();                               // barrier 1: gates ready
        // ---- combine (thread's 4 cells, same (lane,reg) slot, mtile=wv) ----
        f32x4 is = __builtin_bit_cast(f32x4, *(const float4*)&g_lds[0*4 + wv][l][0]);
        f32x4 fs = __builtin_bit_cast(f32x4, *(const float4*)&g_lds[1*4 + wv][l][0]);
        f32x4 gs = __builtin_bit_cast(f32x4, *(const float4*)&g_lds[2*4 + wv][l][0]);
        f32x4 os = __builtin_bit_cast(f32x4, *(const float4*)&g_lds[3*4 + wv][l][0]);
        float hh[4];
        #pragma unroll
        for (int r = 0; r < 4; r++) {
            cst[r] = fs[r] * cst[r] + is[r] * gs[r];
            hh[r]  = os[r] * tanh_f(cst[r]);
        }
        *(float4*)(hq + (size_t)b * (NAG * HSZ)) =
            make_float4(hh[0], hh[1], hh[2], hh[3]);     // global (vmcnt, async)
        int2 pw;
        pw.x = packh2(hh[0], hh[1]);
        pw.y = packh2(hh[2], hh[3]);
        *(int2*)&hp_lds[a][wv*8 + rg*2] = pw;            // h pairs for next B
        lds_barrier();                               // barrier 2: h ready
        #pragma unroll
        for (int kt = 0; kt < 2; kt++) {
            int4 pk = *(const int4*)&hp_lds[a][kt*16 + rg*4];
            bfrag[kt] = __builtin_bit_cast(f16x8, pk);
        }
    };

    for (int b = 0; b < BSZ; b += 2) {
        #pragma unroll
        for (int mt = 0; mt < 4; mt++)               // prefetch X for b+1
            xb[mt] = *(const float4*)(Xb + (size_t)(b + 1) * 4096 + mt*16);
        step(b, xa);
        if (b + 2 < BSZ) {
            #pragma unroll
            for (int mt = 0; mt < 4; mt++)           // prefetch X for b+2
                xa[mt] = *(const float4*)(Xb + (size_t)(b + 2) * 4096 + mt*16);
        }
        step(b + 1, xb);
    }
}

// ---------------------------------------------------------------------------
// Decode: q[b,n,a] = hidden[b,n,:] . Wd[n,a,:] + bd[n,a]. Memory-bound.
// ---------------------------------------------------------------------------
__global__ __launch_bounds__(256) void decode_kernel(
    const float* __restrict__ hid, const float* __restrict__ Wd,
    const float* __restrict__ bd, float* __restrict__ q)
{
    int g   = blockIdx.x * 256 + threadIdx.x;   // [0, B*N*A)
    int row = g >> 4;                            // b*16+n
    int a   = g & 15;
    int n   = row & 15;
    const float4* hr = (const float4*)(hid + (size_t)row * 64);
    const float4* wr = (const float4*)(Wd + ((size_t)n * 16 + a) * 64);
    float s0 = 0.f, s1 = 0.f, s2 = 0.f, s3 = 0.f;
    #pragma unroll
    for (int u = 0; u < 16; u += 4) {
        float4 h0 = hr[u+0], h1 = hr[u+1], h2v = hr[u+2], h3 = hr[u+3];
        float4 w0 = wr[u+0], w1 = wr[u+1], w2 = wr[u+2], w3 = wr[u+3];
        s0 += h0.x*w0.x + h0.y*w0.y + h0.z*w0.z + h0.w*w0.w;
        s1 += h1.x*w1.x + h1.y*w1.y + h1.z*w1.z + h1.w*w1.w;
        s2 += h2v.x*w2.x + h2v.y*w2.y + h2v.z*w2.z + h2v.w*w2.w;
        s3 += h3.x*w3.x + h3.y*w3.y + h3.z*w3.z + h3.w*w3.w;
    }
    q[g] = bd[n * 16 + a] + ((s0 + s1) + (s2 + s3));
}

extern "C" void kernel_launch(void* const* d_in, const int* in_sizes, int n_in,
                              void* d_out, int out_size, void* d_ws, size_t ws_size,
                              hipStream_t stream) {
    const float* obs    = (const float*)d_in[0];
    const float* lstm_h = (const float*)d_in[1];
    const float* lstm_s = (const float*)d_in[2];
    const float* comm   = (const float*)d_in[3];
    const float* W1     = (const float*)d_in[4];
    const float* b1     = (const float*)d_in[5];
    const float* W2     = (const float*)d_in[6];
    const float* b2     = (const float*)d_in[7];
    const float* W_ih   = (const float*)d_in[8];
    const float* W_hh   = (const float*)d_in[9];
    const float* b_ih   = (const float*)d_in[10];
    const float* b_hh   = (const float*)d_in[11];
    const float* Wd     = (const float*)d_in[12];
    const float* bd     = (const float*)d_in[13];
    float* q   = (float*)d_out;

    float* X   = (float*)d_ws;                       // (B*N, 256) f32 = 128 MB
    float* hid = (float*)d_ws + (size_t)BSZ * NAG * 256;  // (B*N, 64) f32 = 32 MB
    (void)in_sizes; (void)n_in; (void)out_size; (void)ws_size;

    encode_kernel<<<dim3(128, 16), 256, 0, stream>>>(obs, comm, W1, b1, W2, b2,
                                                     W_ih, b_ih, b_hh, X);
    scan_kernel<<<1, 256, 0, stream>>>(X, W_hh, lstm_h, lstm_s, hid);
    decode_kernel<<<(BSZ * NAG * 16) / 256, 256, 0, stream>>>(hid, Wd, bd, q);
}